// Round 2
// baseline (224.252 us; speedup 1.0000x reference)
//
#include <hip/hip_runtime.h>
#include <hip/hip_bf16.h>

// SimCSE loss: loss = mean_i( logsumexp_j(sim[i][j]) - sim[i][i] ),
// sim = normalize(q) @ normalize(c)^T / 0.05
// N=8192, D=768, fp32 inputs, scalar fp32 output.

#define NROWS 8192
#define DDIM  768
#define BM 128
#define BN 128
#define BK 64
#define NT (NROWS / BN)        // 64 column tiles
#define TILES_K (DDIM / BK)    // 12

constexpr float INV_TEMP = 20.0f;   // 1/0.05
constexpr float NORM_EPS = 1e-8f;

using bf16 = __hip_bfloat16;
typedef __attribute__((ext_vector_type(4))) float  f32x4;
typedef __attribute__((ext_vector_type(8))) short  bf16x8;

// ---------------------------------------------------------------- normalize
// One block per row (blocks 0..N-1 -> q, N..2N-1 -> c). 256 threads, 3 floats each.
__global__ void normalize_kernel(const float* __restrict__ q,
                                 const float* __restrict__ c,
                                 bf16* __restrict__ qn, bf16* __restrict__ cn,
                                 float* __restrict__ invq, float* __restrict__ invc) {
    int row = blockIdx.x;
    const float* src;
    bf16* dst;
    float* invp;
    if (row < NROWS) {
        src = q + (size_t)row * DDIM; dst = qn + (size_t)row * DDIM; invp = invq + row;
    } else {
        int r = row - NROWS;
        src = c + (size_t)r * DDIM; dst = cn + (size_t)r * DDIM; invp = invc + r;
    }
    int t = threadIdx.x;
    float v0 = src[t], v1 = src[t + 256], v2 = src[t + 512];
    float ss = v0 * v0 + v1 * v1 + v2 * v2;
    #pragma unroll
    for (int m = 32; m; m >>= 1) ss += __shfl_xor(ss, m);
    __shared__ float wsum[4];
    if ((t & 63) == 0) wsum[t >> 6] = ss;
    __syncthreads();
    float tot = wsum[0] + wsum[1] + wsum[2] + wsum[3];
    float inv = 1.0f / fmaxf(sqrtf(tot), NORM_EPS);
    if (t == 0) *invp = inv;
    dst[t]       = __float2bfloat16(v0 * inv);
    dst[t + 256] = __float2bfloat16(v1 * inv);
    dst[t + 512] = __float2bfloat16(v2 * inv);
}

// ---------------------------------------------------------------- diag (fp32)
// 4 waves per block, one row per wave. diag[i] = 20 * invq[i]*invc[i]*dot(q_i,c_i)
__global__ void diag_kernel(const float* __restrict__ q, const float* __restrict__ c,
                            const float* __restrict__ invq, const float* __restrict__ invc,
                            float* __restrict__ diag) {
    int wid = threadIdx.x >> 6, lane = threadIdx.x & 63;
    int row = blockIdx.x * 4 + wid;
    const float* qr = q + (size_t)row * DDIM;
    const float* cr = c + (size_t)row * DDIM;
    float dot = 0.f;
    #pragma unroll
    for (int j = 0; j < DDIM / 64; ++j) dot += qr[lane + j * 64] * cr[lane + j * 64];
    #pragma unroll
    for (int m = 32; m; m >>= 1) dot += __shfl_xor(dot, m);
    if (lane == 0) diag[row] = dot * invq[row] * invc[row] * INV_TEMP;
}

// ---------------------------------------------------------------- GEMM + expsum
__device__ __forceinline__ void async_copy16(bf16* lds_dst, const bf16* g_src) {
    __builtin_amdgcn_global_load_lds(
        (const __attribute__((address_space(1))) void*)g_src,
        (__attribute__((address_space(3))) void*)lds_dst,
        16, 0, 0);
}

// 128x128 tile, 4 waves (2x2), 4x4 16x16x32 fragments per wave, BK=64 staging.
// Epilogue: p = exp(20*acc - 20), row-sum within tile -> partial[row][tn].
__global__ void simgemm_kernel(const bf16* __restrict__ A, const bf16* __restrict__ B,
                               float* __restrict__ partial) {
    __shared__ bf16 Alds[BM][BK];
    __shared__ bf16 Blds[BN][BK];
    __shared__ float red[BM][2];

    int bid = blockIdx.x;
    int tm = bid / NT, tn = bid % NT;
    int rowBase = tm * BM, colBase = tn * BN;
    int tid = threadIdx.x;
    int wid = tid >> 6, lane = tid & 63;
    int wr = wid >> 1, wc = wid & 1;

    f32x4 acc[4][4] = {};

    // staging: wave 'wid' covers rows wid*32..+32 of each tile via 4 instrs of 8 rows
    const int srow = wid * 32 + (lane >> 3);
    const int scol = (lane & 7) * 8;
    const bf16* ag = A + (size_t)(rowBase + srow) * DDIM + scol;
    const bf16* bg = B + (size_t)(colBase + srow) * DDIM + scol;
    bf16* alb = &Alds[wid * 32][0];
    bf16* blb = &Blds[wid * 32][0];

    for (int kt = 0; kt < TILES_K; ++kt) {
        int k0 = kt * BK;
        #pragma unroll
        for (int j = 0; j < 4; ++j) {
            async_copy16(alb + j * 8 * BK, ag + (size_t)j * 8 * DDIM + k0);
            async_copy16(blb + j * 8 * BK, bg + (size_t)j * 8 * DDIM + k0);
        }
        __syncthreads();

        #pragma unroll
        for (int kk = 0; kk < BK; kk += 32) {
            const int kele = kk + (lane >> 4) * 8;
            const int arow = wr * 64 + (lane & 15);
            const int brow = wc * 64 + (lane & 15);
            bf16x8 afrag[4], bfrag[4];
            #pragma unroll
            for (int m = 0; m < 4; ++m)
                afrag[m] = *(const bf16x8*)&Alds[arow + m * 16][kele];
            #pragma unroll
            for (int n = 0; n < 4; ++n)
                bfrag[n] = *(const bf16x8*)&Blds[brow + n * 16][kele];
            #pragma unroll
            for (int m = 0; m < 4; ++m)
                #pragma unroll
                for (int n = 0; n < 4; ++n)
                    acc[m][n] = __builtin_amdgcn_mfma_f32_16x16x32_bf16(
                        afrag[m], bfrag[n], acc[m][n], 0, 0, 0);
        }
        __syncthreads();
    }

    // epilogue: row sums of exp(20*acc - 20) over this tile's 128 columns
    // C/D layout: col = lane&15, row = (lane>>4)*4 + r
    #pragma unroll
    for (int m = 0; m < 4; ++m) {
        float rs[4];
        #pragma unroll
        for (int r = 0; r < 4; ++r) {
            float s = 0.f;
            #pragma unroll
            for (int n = 0; n < 4; ++n)
                s += __expf(fmaf(INV_TEMP, acc[m][n][r], -INV_TEMP));
            s += __shfl_xor(s, 1);
            s += __shfl_xor(s, 2);
            s += __shfl_xor(s, 4);
            s += __shfl_xor(s, 8);
            rs[r] = s;
        }
        if ((lane & 15) == 0) {
            int rgrp = lane >> 4;
            #pragma unroll
            for (int r = 0; r < 4; ++r)
                red[wr * 64 + m * 16 + rgrp * 4 + r][wc] = rs[r];
        }
    }
    __syncthreads();
    if (tid < BM) {
        float s = red[tid][0] + red[tid][1];
        partial[(size_t)(rowBase + tid) * NT + tn] = s;
    }
}

// ---------------------------------------------------------------- finalize
__global__ void finalize_kernel(const float* __restrict__ partial,
                                const float* __restrict__ diag,
                                float* __restrict__ out) {
    int row = blockIdx.x * 256 + threadIdx.x;
    const float4* p = (const float4*)(partial + (size_t)row * NT);
    float z = 0.f;
    #pragma unroll
    for (int i = 0; i < NT / 4; ++i) {
        float4 v = p[i];
        z += v.x + v.y + v.z + v.w;
    }
    float term = INV_TEMP + logf(z) - diag[row];
    #pragma unroll
    for (int m = 32; m; m >>= 1) term += __shfl_xor(term, m);
    __shared__ float wsum[4];
    if ((threadIdx.x & 63) == 0) wsum[threadIdx.x >> 6] = term;
    __syncthreads();
    if (threadIdx.x == 0) {
        float s = wsum[0] + wsum[1] + wsum[2] + wsum[3];
        atomicAdd(out, s * (1.0f / NROWS));
    }
}

// ---------------------------------------------------------------- launch
extern "C" void kernel_launch(void* const* d_in, const int* in_sizes, int n_in,
                              void* d_out, int out_size, void* d_ws, size_t ws_size,
                              hipStream_t stream) {
    const float* q = (const float*)d_in[0];
    const float* c = (const float*)d_in[1];
    float* out = (float*)d_out;

    char* ws = (char*)d_ws;
    bf16* qn = (bf16*)ws;                                       // N*D*2 bytes
    bf16* cn = (bf16*)(ws + (size_t)NROWS * DDIM * 2);          // N*D*2 bytes
    float* invq = (float*)(ws + (size_t)NROWS * DDIM * 4);      // N floats
    float* invc = invq + NROWS;                                 // N floats
    float* diag = invc + NROWS;                                 // N floats
    float* partial = diag + NROWS;                              // N*NT floats (2 MB)

    hipMemsetAsync(d_out, 0, sizeof(float), stream);

    normalize_kernel<<<2 * NROWS, 256, 0, stream>>>(q, c, qn, cn, invq, invc);
    diag_kernel<<<NROWS / 4, 256, 0, stream>>>(q, c, invq, invc, diag);
    simgemm_kernel<<<(NROWS / BM) * (NROWS / BN), 256, 0, stream>>>(qn, cn, partial);
    finalize_kernel<<<NROWS / 256, 256, 0, stream>>>(partial, diag, out);
}

// Round 3
// 193.310 us; speedup vs baseline: 1.1601x; 1.1601x over previous
//
#include <hip/hip_runtime.h>
#include <hip/hip_bf16.h>

// SimCSE loss: loss = mean_i( logsumexp_j(sim[i][j]) - sim[i][i] ),
// sim = normalize(q) @ normalize(c)^T / 0.05.  N=8192, D=768, fp32 in, scalar out.
//
// GEMM: 256x256 tile 8-phase schedule (plain-HIP port of the m201 template):
//  - 512 threads = 8 waves (2 M x 4 N), per-wave output 128x64 (8x4 16x16x32 frags)
//  - BK=64, 2 K-tiles per iteration (12 K-tiles total -> 6 iterations)
//  - LDS 128 KiB: 2 parities x (A: 2x16KB halves + B: 2x16KB halves)
//  - global_load_lds (16B) with linear LDS dest + PRE-SWIZZLED global source;
//    ds_read applies the same XOR swizzle: byte ^= (row&7)<<4  (2-way conflicts)
//  - raw s_barrier; counted vmcnt(4) only at phases 4 and 8; setprio around MFMA

#define NROWS 8192
#define DDIM  768
#define ROWB  1536              // bytes per row (768 * 2B bf16 ... for bf16 mats)
#define FROWB 3072              // bytes per row fp32
#define BK 64
#define NKT  (DDIM / BK)        // 12 K-tiles
#define NIT  (NKT / 2)          // 6 iterations
#define GRID_T (NROWS / 256)    // 32 tiles per dim

constexpr float INV_TEMP = 20.0f;   // 1/0.05
constexpr float NORM_EPS = 1e-8f;

using bf16 = __hip_bfloat16;
typedef __attribute__((ext_vector_type(4))) float  f32x4;
typedef __attribute__((ext_vector_type(8))) short  bf16x8;

// ---------------------------------------------------------------- fused normalize + diag
// One block (192 threads) per row-index i: reads q_i, c_i once; writes bf16
// qn_i, cn_i and diag[i] = 20 * <q_i,c_i> / (|q_i||c_i|)  (all fp32 math).
__global__ void norm_diag_kernel(const float* __restrict__ q, const float* __restrict__ c,
                                 bf16* __restrict__ qn, bf16* __restrict__ cn,
                                 float* __restrict__ diag) {
    int row = blockIdx.x, t = threadIdx.x;
    const float4* qv = (const float4*)(q + (size_t)row * DDIM);
    const float4* cv = (const float4*)(c + (size_t)row * DDIM);
    float4 a = qv[t], b = cv[t];
    float ssq = a.x * a.x + a.y * a.y + a.z * a.z + a.w * a.w;
    float ssc = b.x * b.x + b.y * b.y + b.z * b.z + b.w * b.w;
    float dot = a.x * b.x + a.y * b.y + a.z * b.z + a.w * b.w;
    #pragma unroll
    for (int m = 32; m; m >>= 1) {
        ssq += __shfl_xor(ssq, m);
        ssc += __shfl_xor(ssc, m);
        dot += __shfl_xor(dot, m);
    }
    __shared__ float w3[3][4];
    if ((t & 63) == 0) { w3[t >> 6][0] = ssq; w3[t >> 6][1] = ssc; w3[t >> 6][2] = dot; }
    __syncthreads();
    float SSQ = w3[0][0] + w3[1][0] + w3[2][0];
    float SSC = w3[0][1] + w3[1][1] + w3[2][1];
    float DOT = w3[0][2] + w3[1][2] + w3[2][2];
    float invq = 1.0f / fmaxf(sqrtf(SSQ), NORM_EPS);
    float invc = 1.0f / fmaxf(sqrtf(SSC), NORM_EPS);
    if (t == 0) diag[row] = DOT * invq * invc * INV_TEMP;
    union { ushort4 u; bf16 h[4]; } oq, oc;
    oq.h[0] = __float2bfloat16(a.x * invq); oq.h[1] = __float2bfloat16(a.y * invq);
    oq.h[2] = __float2bfloat16(a.z * invq); oq.h[3] = __float2bfloat16(a.w * invq);
    oc.h[0] = __float2bfloat16(b.x * invc); oc.h[1] = __float2bfloat16(b.y * invc);
    oc.h[2] = __float2bfloat16(b.z * invc); oc.h[3] = __float2bfloat16(b.w * invc);
    ((ushort4*)(qn + (size_t)row * DDIM))[t] = oq.u;
    ((ushort4*)(cn + (size_t)row * DDIM))[t] = oc.u;
}

// ---------------------------------------------------------------- GEMM + expsum
__device__ __forceinline__ void async16(void* l, const void* g) {
    __builtin_amdgcn_global_load_lds(
        (const __attribute__((address_space(1))) void*)g,
        (__attribute__((address_space(3))) void*)l, 16, 0, 0);
}

#define BARRIER __builtin_amdgcn_s_barrier()
#define SCHED0  __builtin_amdgcn_sched_barrier(0)
#define PRIO1   __builtin_amdgcn_s_setprio(1)
#define PRIO0   __builtin_amdgcn_s_setprio(0)
#define LGKM0   do { asm volatile("s_waitcnt lgkmcnt(0)" ::: "memory"); SCHED0; } while (0)
#define VMCNT(n) do { asm volatile("s_waitcnt vmcnt(" #n ")" ::: "memory"); SCHED0; } while (0)

// LDS map (bytes): parity p: A at p*65536, B at 32768 + p*65536; half h at +h*16384.
// Stage one half-tile (128 rows x 64 cols bf16 = 16 KB): 2 x global_load_lds per thread.
#define STAGE_A(P, H, KT) do {                                              \
    const char* _g = aG + (size_t)(H) * 128 * ROWB + (size_t)(KT) * 128;    \
    char* _l = lds + (P) * 65536 + (H) * 16384 + dstW;                      \
    async16(_l, _g);                                                        \
    async16(_l + 8192, _g + 64 * ROWB);                                     \
} while (0)
#define STAGE_B(P, H, KT) do {                                              \
    const char* _g = bG + (size_t)(H) * 128 * ROWB + (size_t)(KT) * 128;    \
    char* _l = lds + 32768 + (P) * 65536 + (H) * 16384 + dstW;              \
    async16(_l, _g);                                                        \
    async16(_l + 8192, _g + 64 * ROWB);                                     \
} while (0)

// ds_read of A fragments for quadrant row-half MH (8 x ds_read_b128)
#define READ_A(P, MH) do {                                                  \
    const char* _ab = lds + (P) * 65536 + aBaseT + (MH) * 64 * 128;         \
    _Pragma("unroll") for (int mi = 0; mi < 4; ++mi) {                      \
        a[mi][0] = *(const bf16x8*)(_ab + mi * 2048 + xk0);                 \
        a[mi][1] = *(const bf16x8*)(_ab + mi * 2048 + xk1);                 \
    }                                                                       \
} while (0)
// ds_read of B fragments for quadrant col-half NH (4 x ds_read_b128)
#define READ_B(P, NH) do {                                                  \
    const char* _bb = lds + 32768 + (P) * 65536 + bBaseT + (NH) * 32 * 128; \
    _Pragma("unroll") for (int ni = 0; ni < 2; ++ni) {                      \
        bfr[NH][ni][0] = *(const bf16x8*)(_bb + ni * 2048 + xk0);           \
        bfr[NH][ni][1] = *(const bf16x8*)(_bb + ni * 2048 + xk1);           \
    }                                                                       \
} while (0)

// 16 MFMA: quadrant (MH, NH), K=64 (2 k-subs), accumulate in place
#define MFMA_Q(MH, NH)                                                      \
    _Pragma("unroll") for (int mi = 0; mi < 4; ++mi)                        \
    _Pragma("unroll") for (int ni = 0; ni < 2; ++ni) {                      \
        acc[(MH)*4+mi][(NH)*2+ni] = __builtin_amdgcn_mfma_f32_16x16x32_bf16(\
            a[mi][0], bfr[NH][ni][0], acc[(MH)*4+mi][(NH)*2+ni], 0, 0, 0);  \
        acc[(MH)*4+mi][(NH)*2+ni] = __builtin_amdgcn_mfma_f32_16x16x32_bf16(\
            a[mi][1], bfr[NH][ni][1], acc[(MH)*4+mi][(NH)*2+ni], 0, 0, 0);  \
    }

__launch_bounds__(512, 2)
__global__ void simgemm_kernel(const bf16* __restrict__ A, const bf16* __restrict__ B,
                               float* __restrict__ partial) {
    __shared__ __attribute__((aligned(16))) char smem[131072];
    char* lds = smem;

    const int bid = blockIdx.x;
    const int tm = bid >> 5, tn = bid & 31;
    const int rowBase = tm * 256, colBase = tn * 256;
    const int tid = threadIdx.x;
    const int wid = tid >> 6, lane = tid & 63;
    const int wr = wid >> 2, wc = wid & 3;

    // staging source (pre-swizzled): thread covers logical rows sr (j=0) and
    // 64+sr (j=1) of each half, col bytes scb..scb+15, where
    // scb = ((tid&7)*16) ^ ((sr&7)<<4)   [involution; read side applies same XOR]
    const int sr  = tid >> 3;
    const int scb = ((tid & 7) * 16) ^ ((sr & 7) << 4);
    const char* aG = (const char*)A + (size_t)(rowBase + sr) * ROWB + scb;
    const char* bG = (const char*)B + (size_t)(colBase + sr) * ROWB + scb;
    const int dstW = wid * 1024;

    // ds_read addressing: A row = wr*128 + MH*64 + mi*16 + (lane&15)
    //   byte = half(=wr)*16384 + lrow*128 + ((ks*64 + (lane>>4)*16) ^ ((lane&7)<<4))
    const int aBaseT = wr * 16384 + (lane & 15) * 128;
    const int bBaseT = (wc >> 1) * 16384 + ((wc & 1) * 64 + (lane & 15)) * 128;
    const int klane  = (lane >> 4) * 16;
    const int swz    = (lane & 7) << 4;
    const int xk0    = klane ^ swz;
    const int xk1    = (64 + klane) ^ swz;

    f32x4  acc[8][4] = {};
    bf16x8 a[4][2];
    bf16x8 bfr[2][2][2];

    // ---- prologue: stage tile0 (buf0) fully + tile1 A halves (buf1)
    STAGE_A(0, 0, 0); STAGE_A(0, 1, 0);
    STAGE_B(0, 0, 0); STAGE_B(0, 1, 0);
    STAGE_A(1, 0, 1); STAGE_A(1, 1, 1);
    VMCNT(4);          // tile0 landed; tile1.A (4 loads) in flight
    BARRIER; SCHED0;

    for (int i = 0; i < NIT; ++i) {
        const int t1 = 2 * i + 1;
        const int t2 = 2 * i + 2, t3 = 2 * i + 3;
        const bool more = (i + 1 < NIT);
        // ph1: read t0 A-half0 + B-half0 frags; stage t1.B0
        READ_A(0, 0); READ_B(0, 0);
        STAGE_B(1, 0, t1);
        BARRIER; LGKM0; PRIO1; MFMA_Q(0, 0); PRIO0; BARRIER; SCHED0;
        // ph2: read t0 B-half1; stage t1.B1
        READ_B(0, 1);
        STAGE_B(1, 1, t1);
        BARRIER; LGKM0; PRIO1; MFMA_Q(0, 1); PRIO0; BARRIER; SCHED0;
        // ph3: read t0 A-half1; stage t2.A0 (buf0 free: all t0 reads done ph2)
        READ_A(0, 1);
        if (more) STAGE_A(0, 0, t2);
        BARRIER; LGKM0; PRIO1; MFMA_Q(1, 0); PRIO0; BARRIER; SCHED0;
        // ph4: stage t2.A1; ensure t1 fully landed before ph5 reads
        if (more) STAGE_A(0, 1, t2);
        BARRIER; LGKM0; PRIO1; MFMA_Q(1, 1); PRIO0;
        if (more) { VMCNT(4); } else { VMCNT(0); }
        BARRIER; SCHED0;
        // ph5: read t1 A-half0 + B-half0; stage t2.B0
        READ_A(1, 0); READ_B(1, 0);
        if (more) STAGE_B(0, 0, t2);
        BARRIER; LGKM0; PRIO1; MFMA_Q(0, 0); PRIO0; BARRIER; SCHED0;
        // ph6: read t1 B-half1; stage t2.B1
        READ_B(1, 1);
        if (more) STAGE_B(0, 1, t2);
        BARRIER; LGKM0; PRIO1; MFMA_Q(0, 1); PRIO0; BARRIER; SCHED0;
        // ph7: read t1 A-half1; stage t3.A0 (buf1 free: all t1 reads done ph6)
        READ_A(1, 1);
        if (more) STAGE_A(1, 0, t3);
        BARRIER; LGKM0; PRIO1; MFMA_Q(1, 0); PRIO0; BARRIER; SCHED0;
        // ph8: stage t3.A1; ensure t2 landed before next ph1 reads
        if (more) STAGE_A(1, 1, t3);
        BARRIER; LGKM0; PRIO1; MFMA_Q(1, 1); PRIO0;
        if (more) { VMCNT(4); }
        BARRIER; SCHED0;
    }

    // ---- epilogue: rowsum of exp(20*acc - 20) over this tile's 256 cols
    __syncthreads();                       // all staging drained (last iter stages nothing past ph2)
    float* red = (float*)smem;             // [256][4]
    #pragma unroll
    for (int m = 0; m < 8; ++m) {
        #pragma unroll
        for (int r = 0; r < 4; ++r) {
            float s = 0.f;
            #pragma unroll
            for (int n = 0; n < 4; ++n)
                s += __expf(fmaf(INV_TEMP, acc[m][n][r], -INV_TEMP));
            s += __shfl_xor(s, 1);
            s += __shfl_xor(s, 2);
            s += __shfl_xor(s, 4);
            s += __shfl_xor(s, 8);
            if ((lane & 15) == 0)
                red[(wr * 128 + m * 16 + (lane >> 4) * 4 + r) * 4 + wc] = s;
        }
    }
    __syncthreads();
    if (tid < 256)
        partial[(size_t)(rowBase + tid) * GRID_T + tn] =
            red[tid * 4 + 0] + red[tid * 4 + 1] + red[tid * 4 + 2] + red[tid * 4 + 3];
}

// ---------------------------------------------------------------- finalize
__global__ void finalize_kernel(const float* __restrict__ partial,
                                const float* __restrict__ diag,
                                float* __restrict__ out) {
    int row = blockIdx.x * 256 + threadIdx.x;
    const float4* p = (const float4*)(partial + (size_t)row * GRID_T);
    float z = 0.f;
    #pragma unroll
    for (int i = 0; i < GRID_T / 4; ++i) {
        float4 v = p[i];
        z += v.x + v.y + v.z + v.w;
    }
    float term = INV_TEMP + logf(z) - diag[row];
    #pragma unroll
    for (int m = 32; m; m >>= 1) term += __shfl_xor(term, m);
    __shared__ float wsum[4];
    if ((threadIdx.x & 63) == 0) wsum[threadIdx.x >> 6] = term;
    __syncthreads();
    if (threadIdx.x == 0) {
        float s = wsum[0] + wsum[1] + wsum[2] + wsum[3];
        atomicAdd(out, s * (1.0f / NROWS));
    }
}

// ---------------------------------------------------------------- launch
extern "C" void kernel_launch(void* const* d_in, const int* in_sizes, int n_in,
                              void* d_out, int out_size, void* d_ws, size_t ws_size,
                              hipStream_t stream) {
    const float* q = (const float*)d_in[0];
    const float* c = (const float*)d_in[1];
    float* out = (float*)d_out;

    char* ws = (char*)d_ws;
    bf16* qn = (bf16*)ws;                                        // 12.6 MB
    bf16* cn = (bf16*)(ws + (size_t)NROWS * DDIM * 2);           // 12.6 MB
    float* diag = (float*)(ws + (size_t)NROWS * DDIM * 4);       // 32 KB
    float* partial = diag + NROWS;                               // 8192*32 floats = 1 MB

    hipMemsetAsync(d_out, 0, sizeof(float), stream);

    norm_diag_kernel<<<NROWS, 192, 0, stream>>>(q, c, qn, cn, diag);
    simgemm_kernel<<<GRID_T * GRID_T, 512, 0, stream>>>(qn, cn, partial);
    finalize_kernel<<<NROWS / 256, 256, 0, stream>>>(partial, diag, out);
}

// Round 4
// 193.114 us; speedup vs baseline: 1.1612x; 1.0010x over previous
//
#include <hip/hip_runtime.h>
#include <hip/hip_bf16.h>

// SimCSE loss: loss = mean_i( logsumexp_j(sim[i][j]) - sim[i][i] ),
// sim = normalize(q) @ normalize(c)^T / 0.05.  N=8192, D=768, fp32 in, scalar out.
//
// GEMM: 256x256 tile 8-phase schedule (m201 template port):
//  - 512 threads = 8 waves (2 M x 4 N), per-wave output 128x64 (8x4 16x16x32 frags)
//  - BK=64, 2 K-tiles per iteration (12 K-tiles -> 6 iterations)
//  - LDS 128 KiB double-buffered; global_load_lds(16B) linear dest with
//    PRE-SWIZZLED global source; ds_read applies same XOR: byte ^= (row&7)<<4
//  - raw s_barrier; counted vmcnt(4) at phases 4/8; setprio around MFMA
//  - NO forced lgkmcnt(0): compiler emits partial lgkm waits so ds_read drain
//    overlaps the MFMA cluster (round-4 change; was the 37%-MfmaUtil stall)
//  - XCD-aware supertile swizzle (8x4 supertiles per XCD round ~ 4.7MB ~ L2)

#define NROWS 8192
#define DDIM  768
#define ROWB  1536              // bytes per bf16 row
#define NKT  (DDIM / 64)        // 12 K-tiles
#define NIT  (NKT / 2)          // 6 iterations
#define GRID_T (NROWS / 256)    // 32 tiles per dim

constexpr float INV_TEMP = 20.0f;   // 1/0.05
constexpr float NORM_EPS = 1e-8f;

using bf16 = __hip_bfloat16;
typedef __attribute__((ext_vector_type(4))) float  f32x4;
typedef __attribute__((ext_vector_type(8))) short  bf16x8;

// ---------------------------------------------------------------- fused normalize + diag
// One WAVE per row i: reads q_i, c_i once; writes bf16 qn_i, cn_i and
// diag[i] = 20 * <q_i,c_i> / (|q_i||c_i|).  No LDS, no block sync.
__global__ void norm_diag_kernel(const float* __restrict__ q, const float* __restrict__ c,
                                 bf16* __restrict__ qn, bf16* __restrict__ cn,
                                 float* __restrict__ diag) {
    const int row  = (blockIdx.x * 256 + threadIdx.x) >> 6;
    const int lane = threadIdx.x & 63;
    const float4* qv = (const float4*)(q + (size_t)row * DDIM);
    const float4* cv = (const float4*)(c + (size_t)row * DDIM);
    float4 a[3], b[3];
    #pragma unroll
    for (int j = 0; j < 3; ++j) { a[j] = qv[lane + j * 64]; b[j] = cv[lane + j * 64]; }
    float ssq = 0.f, ssc = 0.f, dot = 0.f;
    #pragma unroll
    for (int j = 0; j < 3; ++j) {
        ssq += a[j].x * a[j].x + a[j].y * a[j].y + a[j].z * a[j].z + a[j].w * a[j].w;
        ssc += b[j].x * b[j].x + b[j].y * b[j].y + b[j].z * b[j].z + b[j].w * b[j].w;
        dot += a[j].x * b[j].x + a[j].y * b[j].y + a[j].z * b[j].z + a[j].w * b[j].w;
    }
    #pragma unroll
    for (int m = 32; m; m >>= 1) {
        ssq += __shfl_xor(ssq, m);
        ssc += __shfl_xor(ssc, m);
        dot += __shfl_xor(dot, m);
    }
    float invq = 1.0f / fmaxf(sqrtf(ssq), NORM_EPS);
    float invc = 1.0f / fmaxf(sqrtf(ssc), NORM_EPS);
    if (lane == 0) diag[row] = dot * invq * invc * INV_TEMP;
    ushort4* qo = (ushort4*)(qn + (size_t)row * DDIM);
    ushort4* co = (ushort4*)(cn + (size_t)row * DDIM);
    #pragma unroll
    for (int j = 0; j < 3; ++j) {
        union { ushort4 u; bf16 h[4]; } oq, oc;
        oq.h[0] = __float2bfloat16(a[j].x * invq); oq.h[1] = __float2bfloat16(a[j].y * invq);
        oq.h[2] = __float2bfloat16(a[j].z * invq); oq.h[3] = __float2bfloat16(a[j].w * invq);
        oc.h[0] = __float2bfloat16(b[j].x * invc); oc.h[1] = __float2bfloat16(b[j].y * invc);
        oc.h[2] = __float2bfloat16(b[j].z * invc); oc.h[3] = __float2bfloat16(b[j].w * invc);
        qo[lane + j * 64] = oq.u;
        co[lane + j * 64] = oc.u;
    }
}

// ---------------------------------------------------------------- GEMM + expsum
__device__ __forceinline__ void async16(void* l, const void* g) {
    __builtin_amdgcn_global_load_lds(
        (const __attribute__((address_space(1))) void*)g,
        (__attribute__((address_space(3))) void*)l, 16, 0, 0);
}

#define BARRIER __builtin_amdgcn_s_barrier()
#define SCHED0  __builtin_amdgcn_sched_barrier(0)
#define PRIO1   __builtin_amdgcn_s_setprio(1)
#define PRIO0   __builtin_amdgcn_s_setprio(0)
#define VMCNT(n) do { asm volatile("s_waitcnt vmcnt(" #n ")" ::: "memory"); SCHED0; } while (0)

// LDS map (bytes): parity p: A at p*65536, B at 32768 + p*65536; half h at +h*16384.
#define STAGE_A(P, H, KT) do {                                              \
    const char* _g = aG + (size_t)(H) * 128 * ROWB + (size_t)(KT) * 128;    \
    char* _l = lds + (P) * 65536 + (H) * 16384 + dstW;                      \
    async16(_l, _g);                                                        \
    async16(_l + 8192, _g + 64 * ROWB);                                     \
} while (0)
#define STAGE_B(P, H, KT) do {                                              \
    const char* _g = bG + (size_t)(H) * 128 * ROWB + (size_t)(KT) * 128;    \
    char* _l = lds + 32768 + (P) * 65536 + (H) * 16384 + dstW;              \
    async16(_l, _g);                                                        \
    async16(_l + 8192, _g + 64 * ROWB);                                     \
} while (0)

#define READ_A(P, MH) do {                                                  \
    const char* _ab = lds + (P) * 65536 + aBaseT + (MH) * 64 * 128;         \
    _Pragma("unroll") for (int mi = 0; mi < 4; ++mi) {                      \
        a[mi][0] = *(const bf16x8*)(_ab + mi * 2048 + xk0);                 \
        a[mi][1] = *(const bf16x8*)(_ab + mi * 2048 + xk1);                 \
    }                                                                       \
} while (0)
#define READ_B(P, NH) do {                                                  \
    const char* _bb = lds + 32768 + (P) * 65536 + bBaseT + (NH) * 32 * 128; \
    _Pragma("unroll") for (int ni = 0; ni < 2; ++ni) {                      \
        bfr[NH][ni][0] = *(const bf16x8*)(_bb + ni * 2048 + xk0);           \
        bfr[NH][ni][1] = *(const bf16x8*)(_bb + ni * 2048 + xk1);           \
    }                                                                       \
} while (0)

#define MFMA_Q(MH, NH)                                                      \
    _Pragma("unroll") for (int mi = 0; mi < 4; ++mi)                        \
    _Pragma("unroll") for (int ni = 0; ni < 2; ++ni) {                      \
        acc[(MH)*4+mi][(NH)*2+ni] = __builtin_amdgcn_mfma_f32_16x16x32_bf16(\
            a[mi][0], bfr[NH][ni][0], acc[(MH)*4+mi][(NH)*2+ni], 0, 0, 0);  \
        acc[(MH)*4+mi][(NH)*2+ni] = __builtin_amdgcn_mfma_f32_16x16x32_bf16(\
            a[mi][1], bfr[NH][ni][1], acc[(MH)*4+mi][(NH)*2+ni], 0, 0, 0);  \
    }

__launch_bounds__(512, 2)
__global__ void simgemm_kernel(const bf16* __restrict__ A, const bf16* __restrict__ B,
                               float* __restrict__ partial) {
    __shared__ __attribute__((aligned(16))) char smem[131072];
    char* lds = smem;

    // XCD-aware supertile swizzle: nwg=1024, 8 XCDs -> XCD x gets swz chunk
    // [x*128, x*128+128). Within the chunk, 8x4 supertiles (8 A-panels +
    // 4 B-panels ~ 4.7MB) so an XCD round's working set ~ fits its 4MB L2.
    const int bid = blockIdx.x;
    const int swz = (bid & 7) * 128 + (bid >> 3);     // bijective (1024 % 8 == 0)
    const int st = swz >> 5, within = swz & 31;
    const int tm = (st >> 3) * 8 + (within & 7);
    const int tn = (st & 7) * 4 + (within >> 3);
    const int rowBase = tm * 256, colBase = tn * 256;
    const int tid = threadIdx.x;
    const int wid = tid >> 6, lane = tid & 63;
    const int wr = wid >> 2, wc = wid & 3;

    // staging source (pre-swizzled involution; read side applies same XOR)
    const int sr  = tid >> 3;
    const int scb = ((tid & 7) * 16) ^ ((sr & 7) << 4);
    const char* aG = (const char*)A + (size_t)(rowBase + sr) * ROWB + scb;
    const char* bG = (const char*)B + (size_t)(colBase + sr) * ROWB + scb;
    const int dstW = wid * 1024;

    const int aBaseT = wr * 16384 + (lane & 15) * 128;
    const int bBaseT = (wc >> 1) * 16384 + ((wc & 1) * 64 + (lane & 15)) * 128;
    const int klane  = (lane >> 4) * 16;
    const int swzr   = (lane & 7) << 4;
    const int xk0    = klane ^ swzr;
    const int xk1    = (64 + klane) ^ swzr;

    f32x4  acc[8][4] = {};
    bf16x8 a[4][2];
    bf16x8 bfr[2][2][2];

    // ---- prologue: stage tile0 (buf0) fully + tile1 A halves (buf1)
    STAGE_A(0, 0, 0); STAGE_A(0, 1, 0);
    STAGE_B(0, 0, 0); STAGE_B(0, 1, 0);
    STAGE_A(1, 0, 1); STAGE_A(1, 1, 1);
    VMCNT(4);          // tile0 landed; tile1.A (4 loads) in flight
    BARRIER; SCHED0;

    for (int i = 0; i < NIT; ++i) {
        const int t1 = 2 * i + 1;
        const int t2 = 2 * i + 2, t3 = 2 * i + 3;
        const bool more = (i + 1 < NIT);
        // ph1: read t0 A0+B0 frags; stage t1.B0.  (no forced lgkm0: compiler
        // emits partial lgkm waits -> ds_read drain overlaps MFMA cluster)
        READ_A(0, 0); READ_B(0, 0);
        STAGE_B(1, 0, t1);
        BARRIER; PRIO1; MFMA_Q(0, 0); PRIO0; BARRIER; SCHED0;
        // ph2: read t0 B1; stage t1.B1
        READ_B(0, 1);
        STAGE_B(1, 1, t1);
        BARRIER; PRIO1; MFMA_Q(0, 1); PRIO0; BARRIER; SCHED0;
        // ph3: read t0 A1; stage t2.A0 (buf0.A0 free: t0 reads done ph1-2)
        READ_A(0, 1);
        if (more) STAGE_A(0, 0, t2);
        BARRIER; PRIO1; MFMA_Q(1, 0); PRIO0; BARRIER; SCHED0;
        // ph4: stage t2.A1; ensure t1 fully landed before ph5 reads
        if (more) STAGE_A(0, 1, t2);
        BARRIER; PRIO1; MFMA_Q(1, 1); PRIO0;
        if (more) { VMCNT(4); } else { VMCNT(0); }
        BARRIER; SCHED0;
        // ph5: read t1 A0+B0; stage t2.B0
        READ_A(1, 0); READ_B(1, 0);
        if (more) STAGE_B(0, 0, t2);
        BARRIER; PRIO1; MFMA_Q(0, 0); PRIO0; BARRIER; SCHED0;
        // ph6: read t1 B1; stage t2.B1
        READ_B(1, 1);
        if (more) STAGE_B(0, 1, t2);
        BARRIER; PRIO1; MFMA_Q(0, 1); PRIO0; BARRIER; SCHED0;
        // ph7: read t1 A1; stage t3.A0
        READ_A(1, 1);
        if (more) STAGE_A(1, 0, t3);
        BARRIER; PRIO1; MFMA_Q(1, 0); PRIO0; BARRIER; SCHED0;
        // ph8: stage t3.A1; ensure t2 landed before next ph1 reads
        if (more) STAGE_A(1, 1, t3);
        BARRIER; PRIO1; MFMA_Q(1, 1); PRIO0;
        if (more) { VMCNT(4); }
        BARRIER; SCHED0;
    }

    // ---- epilogue: rowsum of exp(20*acc - 20) over this tile's 256 cols
    __syncthreads();
    float* red = (float*)smem;             // [256][4]
    #pragma unroll
    for (int m = 0; m < 8; ++m) {
        #pragma unroll
        for (int r = 0; r < 4; ++r) {
            float s = 0.f;
            #pragma unroll
            for (int n = 0; n < 4; ++n)
                s += __expf(fmaf(INV_TEMP, acc[m][n][r], -INV_TEMP));
            s += __shfl_xor(s, 1);
            s += __shfl_xor(s, 2);
            s += __shfl_xor(s, 4);
            s += __shfl_xor(s, 8);
            if ((lane & 15) == 0)
                red[(wr * 128 + m * 16 + (lane >> 4) * 4 + r) * 4 + wc] = s;
        }
    }
    __syncthreads();
    if (tid < 256)
        partial[(size_t)(rowBase + tid) * GRID_T + tn] =
            red[tid * 4 + 0] + red[tid * 4 + 1] + red[tid * 4 + 2] + red[tid * 4 + 3];
}

// ---------------------------------------------------------------- finalize
__global__ void finalize_kernel(const float* __restrict__ partial,
                                const float* __restrict__ diag,
                                float* __restrict__ out) {
    int row = blockIdx.x * 256 + threadIdx.x;
    const float4* p = (const float4*)(partial + (size_t)row * GRID_T);
    float z = 0.f;
    #pragma unroll
    for (int i = 0; i < GRID_T / 4; ++i) {
        float4 v = p[i];
        z += v.x + v.y + v.z + v.w;
    }
    float term = INV_TEMP + logf(z) - diag[row];
    #pragma unroll
    for (int m = 32; m; m >>= 1) term += __shfl_xor(term, m);
    __shared__ float wsum[4];
    if ((threadIdx.x & 63) == 0) wsum[threadIdx.x >> 6] = term;
    __syncthreads();
    if (threadIdx.x == 0) {
        float s = wsum[0] + wsum[1] + wsum[2] + wsum[3];
        atomicAdd(out, s * (1.0f / NROWS));
    }
}

// ---------------------------------------------------------------- launch
extern "C" void kernel_launch(void* const* d_in, const int* in_sizes, int n_in,
                              void* d_out, int out_size, void* d_ws, size_t ws_size,
                              hipStream_t stream) {
    const float* q = (const float*)d_in[0];
    const float* c = (const float*)d_in[1];
    float* out = (float*)d_out;

    char* ws = (char*)d_ws;
    bf16* qn = (bf16*)ws;                                        // 12.6 MB
    bf16* cn = (bf16*)(ws + (size_t)NROWS * DDIM * 2);           // 12.6 MB
    float* diag = (float*)(ws + (size_t)NROWS * DDIM * 4);       // 32 KB
    float* partial = diag + NROWS;                               // 1 MB

    hipMemsetAsync(d_out, 0, sizeof(float), stream);

    norm_diag_kernel<<<NROWS / 4, 256, 0, stream>>>(q, c, qn, cn, diag);
    simgemm_kernel<<<GRID_T * GRID_T, 512, 0, stream>>>(qn, cn, partial);
    finalize_kernel<<<NROWS / 256, 256, 0, stream>>>(partial, diag, out);
}

// Round 5
// 191.239 us; speedup vs baseline: 1.1726x; 1.0098x over previous
//
#include <hip/hip_runtime.h>
#include <hip/hip_bf16.h>

// SimCSE loss: loss = mean_i( logsumexp_j(sim[i][j]) - sim[i][i] ),
// sim = normalize(q) @ normalize(c)^T / 0.05.  N=8192, D=768, fp32 in, scalar out.
//
// GEMM: 256x256 tile, 8 waves (2Mx4N), BK=64, 2 K-tiles/iter, 128KiB LDS dbuf.
// Round-5 schedule: ONE barrier per phase, ds_reads software-pipelined one
// phase ahead of their consuming MFMA:
//    phase k body: { STAGE; MFMA_Q(k); [vmcnt]; BARRIER; READS(for k+1) }
// Reads sit directly before their MFMA with no barrier between -> per-wave
// lgkm skew lets the LDS unit serve one wave's reads while another wave's
// MFMAs occupy the matrix pipe (the overlap the 2-barrier structure forbids).

#define NROWS 8192
#define DDIM  768
#define ROWB  1536              // bytes per bf16 row
#define NKT  (DDIM / 64)        // 12 K-tiles
#define NIT  (NKT / 2)          // 6 iterations
#define GRID_T (NROWS / 256)    // 32 tiles per dim

constexpr float INV_TEMP = 20.0f;   // 1/0.05
constexpr float NORM_EPS = 1e-8f;

using bf16 = __hip_bfloat16;
typedef __attribute__((ext_vector_type(4))) float  f32x4;
typedef __attribute__((ext_vector_type(8))) short  bf16x8;

// ---------------------------------------------------------------- fused normalize + diag
__global__ void norm_diag_kernel(const float* __restrict__ q, const float* __restrict__ c,
                                 bf16* __restrict__ qn, bf16* __restrict__ cn,
                                 float* __restrict__ diag) {
    const int row  = (blockIdx.x * 256 + threadIdx.x) >> 6;
    const int lane = threadIdx.x & 63;
    const float4* qv = (const float4*)(q + (size_t)row * DDIM);
    const float4* cv = (const float4*)(c + (size_t)row * DDIM);
    float4 a[3], b[3];
    #pragma unroll
    for (int j = 0; j < 3; ++j) { a[j] = qv[lane + j * 64]; b[j] = cv[lane + j * 64]; }
    float ssq = 0.f, ssc = 0.f, dot = 0.f;
    #pragma unroll
    for (int j = 0; j < 3; ++j) {
        ssq += a[j].x * a[j].x + a[j].y * a[j].y + a[j].z * a[j].z + a[j].w * a[j].w;
        ssc += b[j].x * b[j].x + b[j].y * b[j].y + b[j].z * b[j].z + b[j].w * b[j].w;
        dot += a[j].x * b[j].x + a[j].y * b[j].y + a[j].z * b[j].z + a[j].w * b[j].w;
    }
    #pragma unroll
    for (int m = 32; m; m >>= 1) {
        ssq += __shfl_xor(ssq, m);
        ssc += __shfl_xor(ssc, m);
        dot += __shfl_xor(dot, m);
    }
    float invq = 1.0f / fmaxf(sqrtf(ssq), NORM_EPS);
    float invc = 1.0f / fmaxf(sqrtf(ssc), NORM_EPS);
    if (lane == 0) diag[row] = dot * invq * invc * INV_TEMP;
    ushort4* qo = (ushort4*)(qn + (size_t)row * DDIM);
    ushort4* co = (ushort4*)(cn + (size_t)row * DDIM);
    #pragma unroll
    for (int j = 0; j < 3; ++j) {
        union { ushort4 u; bf16 h[4]; } oq, oc;
        oq.h[0] = __float2bfloat16(a[j].x * invq); oq.h[1] = __float2bfloat16(a[j].y * invq);
        oq.h[2] = __float2bfloat16(a[j].z * invq); oq.h[3] = __float2bfloat16(a[j].w * invq);
        oc.h[0] = __float2bfloat16(b[j].x * invc); oc.h[1] = __float2bfloat16(b[j].y * invc);
        oc.h[2] = __float2bfloat16(b[j].z * invc); oc.h[3] = __float2bfloat16(b[j].w * invc);
        qo[lane + j * 64] = oq.u;
        co[lane + j * 64] = oc.u;
    }
}

// ---------------------------------------------------------------- GEMM + expsum
__device__ __forceinline__ void async16(void* l, const void* g) {
    __builtin_amdgcn_global_load_lds(
        (const __attribute__((address_space(1))) void*)g,
        (__attribute__((address_space(3))) void*)l, 16, 0, 0);
}

#define BARRIER __builtin_amdgcn_s_barrier()
#define SCHED0  __builtin_amdgcn_sched_barrier(0)
#define PRIO1   __builtin_amdgcn_s_setprio(1)
#define PRIO0   __builtin_amdgcn_s_setprio(0)
#define VMCNT(n) do { asm volatile("s_waitcnt vmcnt(" #n ")" ::: "memory"); } while (0)

// LDS map (bytes): parity p: A at p*65536, B at 32768 + p*65536; half h at +h*16384.
#define STAGE_A(P, H, KT) do {                                              \
    const char* _g = aG + (size_t)(H) * 128 * ROWB + (size_t)(KT) * 128;    \
    char* _l = lds + (P) * 65536 + (H) * 16384 + dstW;                      \
    async16(_l, _g);                                                        \
    async16(_l + 8192, _g + 64 * ROWB);                                     \
} while (0)
#define STAGE_B(P, H, KT) do {                                              \
    const char* _g = bG + (size_t)(H) * 128 * ROWB + (size_t)(KT) * 128;    \
    char* _l = lds + 32768 + (P) * 65536 + (H) * 16384 + dstW;              \
    async16(_l, _g);                                                        \
    async16(_l + 8192, _g + 64 * ROWB);                                     \
} while (0)

#define READ_A(P, MH) do {                                                  \
    const char* _ab = lds + (P) * 65536 + aBaseT + (MH) * 64 * 128;         \
    _Pragma("unroll") for (int mi = 0; mi < 4; ++mi) {                      \
        a[mi][0] = *(const bf16x8*)(_ab + mi * 2048 + xk0);                 \
        a[mi][1] = *(const bf16x8*)(_ab + mi * 2048 + xk1);                 \
    }                                                                       \
} while (0)
#define READ_B(P, NH) do {                                                  \
    const char* _bb = lds + 32768 + (P) * 65536 + bBaseT + (NH) * 32 * 128; \
    _Pragma("unroll") for (int ni = 0; ni < 2; ++ni) {                      \
        bfr[NH][ni][0] = *(const bf16x8*)(_bb + ni * 2048 + xk0);           \
        bfr[NH][ni][1] = *(const bf16x8*)(_bb + ni * 2048 + xk1);           \
    }                                                                       \
} while (0)

#define MFMA_Q(MH, NH)                                                      \
    _Pragma("unroll") for (int mi = 0; mi < 4; ++mi)                        \
    _Pragma("unroll") for (int ni = 0; ni < 2; ++ni) {                      \
        acc[(MH)*4+mi][(NH)*2+ni] = __builtin_amdgcn_mfma_f32_16x16x32_bf16(\
            a[mi][0], bfr[NH][ni][0], acc[(MH)*4+mi][(NH)*2+ni], 0, 0, 0);  \
        acc[(MH)*4+mi][(NH)*2+ni] = __builtin_amdgcn_mfma_f32_16x16x32_bf16(\
            a[mi][1], bfr[NH][ni][1], acc[(MH)*4+mi][(NH)*2+ni], 0, 0, 0);  \
    }

__launch_bounds__(512, 2)
__global__ void simgemm_kernel(const bf16* __restrict__ A, const bf16* __restrict__ B,
                               float* __restrict__ partial) {
    __shared__ __attribute__((aligned(16))) char smem[131072];
    char* lds = smem;

    const int bid = blockIdx.x;
    const int tm = bid >> 5, tn = bid & 31;
    const int rowBase = tm * 256, colBase = tn * 256;
    const int tid = threadIdx.x;
    const int wid = tid >> 6, lane = tid & 63;
    const int wr = wid >> 2, wc = wid & 3;

    // staging source (pre-swizzled involution; read side applies same XOR)
    const int sr  = tid >> 3;
    const int scb = ((tid & 7) * 16) ^ ((sr & 7) << 4);
    const char* aG = (const char*)A + (size_t)(rowBase + sr) * ROWB + scb;
    const char* bG = (const char*)B + (size_t)(colBase + sr) * ROWB + scb;
    const int dstW = wid * 1024;

    const int aBaseT = wr * 16384 + (lane & 15) * 128;
    const int bBaseT = (wc >> 1) * 16384 + ((wc & 1) * 64 + (lane & 15)) * 128;
    const int klane  = (lane >> 4) * 16;
    const int swzr   = (lane & 7) << 4;
    const int xk0    = klane ^ swzr;
    const int xk1    = (64 + klane) ^ swzr;

    f32x4  acc[8][4] = {};
    bf16x8 a[4][2];
    bf16x8 bfr[2][2][2];

    // ---- prologue: stage tile0 (buf0) fully + tile1 A halves (buf1)
    STAGE_A(0, 0, 0); STAGE_A(0, 1, 0);
    STAGE_B(0, 0, 0); STAGE_B(0, 1, 0);
    STAGE_A(1, 0, 1); STAGE_A(1, 1, 1);
    VMCNT(4);          // tile0 landed; tile1.A (4 loads) in flight
    BARRIER; SCHED0;
    READ_A(0, 0); READ_B(0, 0);
    SCHED0;

    #pragma unroll 1
    for (int i = 0; i < NIT; ++i) {
        const int t1 = 2 * i + 1;
        const int t2 = 2 * i + 2, t3 = 2 * i + 3;
        const bool more = (i + 1 < NIT);
        // ph1: MFMA t_even(0,0); stage tO.B0 | after bar: read tE.B1
        STAGE_B(1, 0, t1);
        PRIO1; MFMA_Q(0, 0); PRIO0;
        VMCNT(6);
        BARRIER; SCHED0;
        READ_B(0, 1); SCHED0;
        // ph2: MFMA(0,1); stage tO.B1 | read tE.A1
        STAGE_B(1, 1, t1);
        PRIO1; MFMA_Q(0, 1); PRIO0;
        BARRIER; SCHED0;
        READ_A(0, 1); SCHED0;
        // ph3: MFMA(1,0); stage t2.A0
        if (more) STAGE_A(0, 0, t2);
        PRIO1; MFMA_Q(1, 0); PRIO0;
        BARRIER; SCHED0;
        // ph4: MFMA(1,1); stage t2.A1 | read tO.A0, tO.B0
        if (more) STAGE_A(0, 1, t2);
        PRIO1; MFMA_Q(1, 1); PRIO0;
        if (more) { VMCNT(6); } else { VMCNT(0); }
        BARRIER; SCHED0;
        READ_A(1, 0); READ_B(1, 0); SCHED0;
        // ph5: MFMA t_odd(0,0); stage t2.B0 | read tO.B1
        if (more) STAGE_B(0, 0, t2);
        PRIO1; MFMA_Q(0, 0); PRIO0;
        if (more) { VMCNT(6); }
        BARRIER; SCHED0;
        READ_B(1, 1); SCHED0;
        // ph6: MFMA(0,1); stage t2.B1 | read tO.A1
        if (more) STAGE_B(0, 1, t2);
        PRIO1; MFMA_Q(0, 1); PRIO0;
        BARRIER; SCHED0;
        READ_A(1, 1); SCHED0;
        // ph7: MFMA(1,0); stage t3.A0
        if (more) STAGE_A(1, 0, t3);
        PRIO1; MFMA_Q(1, 0); PRIO0;
        BARRIER; SCHED0;
        // ph8: MFMA(1,1); stage t3.A1 | read t2.A0, t2.B0
        if (more) STAGE_A(1, 1, t3);
        PRIO1; MFMA_Q(1, 1); PRIO0;
        if (more) { VMCNT(6); }
        BARRIER; SCHED0;
        if (more) { READ_A(0, 0); READ_B(0, 0); SCHED0; }
    }

    // ---- epilogue: rowsum of exp(20*acc - 20) over this tile's 256 cols
    __syncthreads();                       // all loads drained (VMCNT(0) in last ph4)
    float* red = (float*)smem;             // [256][4]
    #pragma unroll
    for (int m = 0; m < 8; ++m) {
        #pragma unroll
        for (int r = 0; r < 4; ++r) {
            float s = 0.f;
            #pragma unroll
            for (int n = 0; n < 4; ++n)
                s += __expf(fmaf(INV_TEMP, acc[m][n][r], -INV_TEMP));
            s += __shfl_xor(s, 1);
            s += __shfl_xor(s, 2);
            s += __shfl_xor(s, 4);
            s += __shfl_xor(s, 8);
            if ((lane & 15) == 0)
                red[(wr * 128 + m * 16 + (lane >> 4) * 4 + r) * 4 + wc] = s;
        }
    }
    __syncthreads();
    if (tid < 256)
        partial[(size_t)(rowBase + tid) * GRID_T + tn] =
            red[tid * 4 + 0] + red[tid * 4 + 1] + red[tid * 4 + 2] + red[tid * 4 + 3];
}

// ---------------------------------------------------------------- finalize
__global__ void finalize_kernel(const float* __restrict__ partial,
                                const float* __restrict__ diag,
                                float* __restrict__ out) {
    int row = blockIdx.x * 256 + threadIdx.x;
    const float4* p = (const float4*)(partial + (size_t)row * GRID_T);
    float z = 0.f;
    #pragma unroll
    for (int i = 0; i < GRID_T / 4; ++i) {
        float4 v = p[i];
        z += v.x + v.y + v.z + v.w;
    }
    float term = INV_TEMP + logf(z) - diag[row];
    #pragma unroll
    for (int m = 32; m; m >>= 1) term += __shfl_xor(term, m);
    __shared__ float wsum[4];
    if ((threadIdx.x & 63) == 0) wsum[threadIdx.x >> 6] = term;
    __syncthreads();
    if (threadIdx.x == 0) {
        float s = wsum[0] + wsum[1] + wsum[2] + wsum[3];
        atomicAdd(out, s * (1.0f / NROWS));
    }
}

// ---------------------------------------------------------------- launch
extern "C" void kernel_launch(void* const* d_in, const int* in_sizes, int n_in,
                              void* d_out, int out_size, void* d_ws, size_t ws_size,
                              hipStream_t stream) {
    const float* q = (const float*)d_in[0];
    const float* c = (const float*)d_in[1];
    float* out = (float*)d_out;

    char* ws = (char*)d_ws;
    bf16* qn = (bf16*)ws;                                        // 12.6 MB
    bf16* cn = (bf16*)(ws + (size_t)NROWS * DDIM * 2);           // 12.6 MB
    float* diag = (float*)(ws + (size_t)NROWS * DDIM * 4);       // 32 KB
    float* partial = diag + NROWS;                               // 1 MB

    hipMemsetAsync(d_out, 0, sizeof(float), stream);

    norm_diag_kernel<<<NROWS / 4, 256, 0, stream>>>(q, c, qn, cn, diag);
    simgemm_kernel<<<GRID_T * GRID_T, 512, 0, stream>>>(qn, cn, partial);
    finalize_kernel<<<NROWS / 256, 256, 0, stream>>>(partial, diag, out);
}